// Round 11
// baseline (542.782 us; speedup 1.0000x reference)
//
#include <hip/hip_runtime.h>
#include <cstdint>
#include <cstddef>

// ---------------------------------------------------------------------------
// FCAGAT: 3x GATConv (H=2, C=64) + ELU + concat + MLP(384->128->1)
// R10: R9 failed from WORKSPACE OVERFLOW (carve total 128.5 MiB > ws), which
// corrupted harness pristine buffers -> replay divergence. Fix: agg3 stored
// bf16 (61.4->30.7 MB); total ~104 MB (R8-proven 112 MB was safe).
// Pipeline: zeroB, scatter_b, redbkt, scanbkt, then per cat:
//   gemm_att -> build_w (sort + fused per-edge softmax alphas) -> aggregate
// then final_mlp (reads bf16 agg).
// ---------------------------------------------------------------------------

__device__ __forceinline__ float lrelu02(float x) { return x > 0.f ? x : 0.2f * x; }
__device__ __forceinline__ float elu1(float x) { return x > 0.f ? x : (__expf(x) - 1.f); }
__device__ __forceinline__ unsigned short f2bf(float x) {   // RNE bf16
  unsigned int u = __float_as_uint(x);
  return (unsigned short)((u + 0x7FFF + ((u >> 16) & 1)) >> 16);
}
__device__ __forceinline__ float bf2f(unsigned int h) {
  return __uint_as_float(h << 16);
}

#define TM 64
#define TN 128
#define TKK 32
#define SLICES 64
#define CAPX 96                 // per-(bucket,slice): mean ~32, +11 sigma
#define BSTG (SLICES * CAPX)    // 6144 staging slots per bucket
#define BMAX 3072               // max real entries per bucket (mean 2048,+23s)

// ---------------- gemm_att: XW = X[M,K] @ W[K,128] + fused att dots ----------
__global__ __launch_bounds__(256) void gemm_att(
    const float* __restrict__ X, const float* __restrict__ W,
    const float* __restrict__ att_s, const float* __restrict__ att_d,
    float* __restrict__ XW, float* __restrict__ a_src, float* __restrict__ a_dst,
    int M, int K) {
  __shared__ __align__(16) float xs[TKK][TM];     // 8 KB, swizzled transposed A
  __shared__ __align__(16) float4 wsB[TKK][TN/4]; // 16 KB, swizzled B
  const int tid = threadIdx.x;
  const int tx = tid & 15;
  const int ty = tid >> 4;
  const int row0 = blockIdx.x * TM;
  float acc[4][8];
#pragma unroll
  for (int r = 0; r < 4; ++r)
#pragma unroll
    for (int c = 0; c < 8; ++c) acc[r][c] = 0.f;

  const int lr = tid >> 2;
  const int lk = (tid & 3) * 8;
  const int wr = tid >> 3;
  const int bb = (tid & 7) * 4;
  const int xcol = lr ^ (((lk >> 3) & 1) * 16);
  const int p0 = (tx * 2) ^ (2 * ((tx * 2) >> 3));
  const int p1 = (tx * 2 + 1) ^ (2 * ((tx * 2 + 1) >> 3));

  for (int k0 = 0; k0 < K; k0 += TKK) {
    int xrow = row0 + lr; if (xrow >= M) xrow = M - 1;
    const float4* xp = (const float4*)(X + (size_t)xrow * K + k0 + lk);
    float4 xa = xp[0];
    float4 xb = xp[1];
    const float4* wp = (const float4*)(W + (size_t)(k0 + wr) * TN + bb * 4);
    float4 w0 = wp[0], w1 = wp[1], w2 = wp[2], w3 = wp[3];
    __syncthreads();
    xs[lk + 0][xcol] = xa.x; xs[lk + 1][xcol] = xa.y;
    xs[lk + 2][xcol] = xa.z; xs[lk + 3][xcol] = xa.w;
    xs[lk + 4][xcol] = xb.x; xs[lk + 5][xcol] = xb.y;
    xs[lk + 6][xcol] = xb.z; xs[lk + 7][xcol] = xb.w;
    {
      int b0i = bb + 0; wsB[wr][b0i ^ (2 * (b0i >> 3))] = w0;
      int b1i = bb + 1; wsB[wr][b1i ^ (2 * (b1i >> 3))] = w1;
      int b2i = bb + 2; wsB[wr][b2i ^ (2 * (b2i >> 3))] = w2;
      int b3i = bb + 3; wsB[wr][b3i ^ (2 * (b3i >> 3))] = w3;
    }
    __syncthreads();
#pragma unroll
    for (int k = 0; k < TKK; ++k) {
      const int acol = (ty * 4) ^ (((k >> 3) & 1) * 16);
      float4 a = *(const float4*)&xs[k][acol];
      float4 b0 = wsB[k][p0];
      float4 b1 = wsB[k][p1];
      float av[4] = {a.x, a.y, a.z, a.w};
      float bv[8] = {b0.x, b0.y, b0.z, b0.w, b1.x, b1.y, b1.z, b1.w};
#pragma unroll
      for (int r = 0; r < 4; ++r)
#pragma unroll
        for (int c = 0; c < 8; ++c)
          acc[r][c] = fmaf(av[r], bv[c], acc[r][c]);
    }
  }
#pragma unroll
  for (int r = 0; r < 4; ++r) {
    int row = row0 + ty * 4 + r;
    if (row < M) {
      float4 o0 = {acc[r][0], acc[r][1], acc[r][2], acc[r][3]};
      float4 o1 = {acc[r][4], acc[r][5], acc[r][6], acc[r][7]};
      float4* op = (float4*)(XW + (size_t)row * TN + tx * 8);
      op[0] = o0; op[1] = o1;
    }
  }
  // fused attention dots: this thread's 8 cols all belong to head tx>>3
  float ps[4] = {0.f, 0.f, 0.f, 0.f}, pd[4] = {0.f, 0.f, 0.f, 0.f};
#pragma unroll
  for (int c = 0; c < 8; ++c) {
    float as = att_s[tx * 8 + c], ad = att_d[tx * 8 + c];
#pragma unroll
    for (int r = 0; r < 4; ++r) {
      ps[r] = fmaf(acc[r][c], as, ps[r]);
      pd[r] = fmaf(acc[r][c], ad, pd[r]);
    }
  }
#pragma unroll
  for (int off = 1; off < 8; off <<= 1) {
#pragma unroll
    for (int r = 0; r < 4; ++r) {
      ps[r] += __shfl_xor(ps[r], off);
      pd[r] += __shfl_xor(pd[r], off);
    }
  }
  if ((tx & 7) == 0) {
    int head = tx >> 3;
#pragma unroll
    for (int r = 0; r < 4; ++r) {
      int row = row0 + ty * 4 + r;
      if (row < M) {
        a_src[row * 2 + head] = ps[r];
        a_dst[row * 2 + head] = pd[r];
      }
    }
  }
}

// ---------------- zeroB ----------------
__global__ void zeroB(int* __restrict__ a, int n) {
  int i = blockIdx.x * blockDim.x + threadIdx.x;
  if (i < n) a[i] = 0;
}

// ---------------- scatter_b: bucketed edge scatter, 64 slices ----------
__global__ void scatter_b(const int* __restrict__ ei0, const int* __restrict__ ei1,
                          const int* __restrict__ ei2, int E0, int E1, int E2,
                          int Nn, int nbpc, int* __restrict__ bktCnt,
                          int* __restrict__ bkt) {
  int i = blockIdx.x * blockDim.x + threadIdx.x;
  int c1 = E0, c2 = E0 + E1, totE = c2 + E2, tot = totE + 3 * Nn;
  if (i >= tot) return;
  int s, d, cat, slice;
  if (i < totE) {
    if (i < c1)      { s = ei0[i];            d = ei0[E0 + i];      cat = 0; }
    else if (i < c2) { int t = i - c1; s = ei1[t]; d = ei1[E1 + t]; cat = 1; }
    else             { int t = i - c2; s = ei2[t]; d = ei2[E2 + t]; cat = 2; }
    slice = blockIdx.x & (SLICES - 1);    // slice&7 == XCD (round-robin)
  } else {
    int j = i - totE;
    cat = (j < Nn) ? 0 : (j < 2 * Nn) ? 1 : 2;
    int n = j - cat * Nn;
    s = n; d = n;
    slice = (n >> 1) & (SLICES - 1);
  }
  const int bs = (cat * nbpc + (d >> 7)) * SLICES + slice;
  int pos = atomicAdd(&bktCnt[bs * 16], 1);       // 1 counter per 64B line
  if (pos < CAPX) bkt[(size_t)bs * CAPX + pos] = ((d & 127) << 16) | s;
}

// ---------------- redbkt: per-bucket totals ----------------
__global__ __launch_bounds__(64) void redbkt(const int* __restrict__ bktCnt,
                                             int* __restrict__ tot) {
  int b = blockIdx.x, t = threadIdx.x;   // 64 threads
  int v = min(bktCnt[(b * SLICES + t) * 16], CAPX);
#pragma unroll
  for (int off = 32; off; off >>= 1) v += __shfl_xor(v, off);
  if (t == 0) tot[b] = v;
}

// ---------------- scanbkt: exclusive scan of totals (NB <= 1024) -----------
__global__ __launch_bounds__(1024) void scanbkt(const int* __restrict__ tot,
                                                int* __restrict__ bktBase, int NB) {
  __shared__ int tmp[1024];
  int t = threadIdx.x;
  int v = (t < NB) ? tot[t] : 0;
  int orig = v;
  tmp[t] = v;
  __syncthreads();
  for (int off = 1; off < 1024; off <<= 1) {
    int u = (t >= off) ? tmp[t - off] : 0;
    __syncthreads();
    tmp[t] += u;
    __syncthreads();
  }
  if (t < NB) bktBase[t] = tmp[t] - orig;
}

// ---------------- build_w: sort bucket + fused per-edge softmax alphas ------
__global__ __launch_bounds__(256) void build_w(
    const int* __restrict__ bkt, const int* __restrict__ bktCnt,
    const int* __restrict__ bktBase,
    const float2* __restrict__ a_srcC, const float2* __restrict__ a_dstC,
    int* __restrict__ adjS, float2* __restrict__ wE,
    int2* __restrict__ offcnt, int Nn, int nbpc, int cat) {
  __shared__ int cntA[128], scanA[128], fillA[128];
  __shared__ int nsA[SLICES];
  __shared__ int esort[BMAX];
  __shared__ float2 asw[BMAX];
  const int tid = threadIdx.x;
  const int bl = blockIdx.x;
  const int b = cat * nbpc + bl;
  const int dBase = bl << 7;
  const int* stg = bkt + (size_t)b * BSTG;
  if (tid < 128) { cntA[tid] = 0; fillA[tid] = 0; }
  if (tid < SLICES) nsA[tid] = min(bktCnt[(b * SLICES + tid) * 16], CAPX);
  __syncthreads();
  // pass 1: histogram by dLow (flattened over staging slots)
  for (int j = tid; j < BSTG; j += 256) {
    int s = j / CAPX, i = j - s * CAPX;
    if (i < nsA[s]) atomicAdd(&cntA[stg[j] >> 16], 1);
  }
  __syncthreads();
  if (tid < 128) scanA[tid] = cntA[tid];
  __syncthreads();
  for (int off = 1; off < 128; off <<= 1) {
    int t = (tid < 128 && tid >= off) ? scanA[tid - off] : 0;
    __syncthreads();
    if (tid < 128) scanA[tid] += t;
    __syncthreads();
  }
  // pass 2: place src into esort (segment start for node t = scanA[t]-cntA[t])
  for (int j = tid; j < BSTG; j += 256) {
    int s = j / CAPX, i = j - s * CAPX;
    if (i < nsA[s]) {
      int v = stg[j];
      int n = v >> 16;
      int p = scanA[n] - cntA[n] + atomicAdd(&fillA[n], 1);
      esort[p] = v & 0xFFFF;
    }
  }
  __syncthreads();
  const int tot = scanA[127];
  // gather a_src per edge (parallel random loads)
  for (int i = tid; i < tot; i += 256) asw[i] = a_srcC[esort[i]];
  __syncthreads();
  // per-node softmax -> alphas in place (128 parallel nodes)
  if (tid < 128 && dBase + tid < Nn) {
    const float2 ad = a_dstC[dBase + tid];
    const int st = scanA[tid] - cntA[tid], c = cntA[tid];
    float m0 = -1e30f, m1 = -1e30f;
    for (int i = st; i < st + c; ++i) {
      float2 as = asw[i];
      float e0 = lrelu02(as.x + ad.x);
      float e1 = lrelu02(as.y + ad.y);
      asw[i] = make_float2(e0, e1);
      m0 = fmaxf(m0, e0); m1 = fmaxf(m1, e1);
    }
    float s0 = 0.f, s1 = 0.f;
    for (int i = st; i < st + c; ++i) {
      float p0 = __expf(asw[i].x - m0);
      float p1 = __expf(asw[i].y - m1);
      s0 += p0; s1 += p1;
      asw[i] = make_float2(p0, p1);
    }
    const float inv0 = 1.f / s0, inv1 = 1.f / s1;
    for (int i = st; i < st + c; ++i) {
      asw[i].x *= inv0; asw[i].y *= inv1;
    }
  }
  __syncthreads();
  // coalesced flush
  const int gB = bktBase[b];
  for (int i = tid; i < tot; i += 256) {
    adjS[gB + i] = esort[i];
    wE[gB + i] = asw[i];
  }
  if (tid < 128 && dBase + tid < Nn)
    offcnt[(size_t)cat * Nn + dBase + tid] =
        make_int2(gB + scanA[tid] - cntA[tid], cntA[tid]);
}

// ---------------- aggregate: pure stream + gather + fma, bf16 output --------
__global__ __launch_bounds__(256) void aggregate(
    const float* __restrict__ xw, const int2* __restrict__ offcnt,
    const int* __restrict__ adjS, const float2* __restrict__ wE,
    unsigned short* __restrict__ agg, int Nn) {
  const int node = (int)((blockIdx.x * (size_t)blockDim.x + threadIdx.x) >> 6);
  const int lane = threadIdx.x & 63;
  if (node >= Nn) return;
  const int2 oc = offcnt[node];
  const int base = oc.x, end = oc.x + oc.y;
  float acc0 = 0.f, acc1 = 0.f;
  for (int cb = base; cb < end; cb += 64) {
    const int cnt = min(64, end - cb);
    int srcv = 0; float w0v = 0.f, w1v = 0.f;
    if (lane < cnt) {
      srcv = adjS[cb + lane];
      float2 w = wE[cb + lane];
      w0v = w.x; w1v = w.y;
    }
    int k = 0;
    for (; k + 4 <= cnt; k += 4) {
      int sa = __shfl(srcv, k),     sb = __shfl(srcv, k + 1);
      int sc = __shfl(srcv, k + 2), sd = __shfl(srcv, k + 3);
      float wa0 = __shfl(w0v, k),     wb0 = __shfl(w0v, k + 1);
      float wc0 = __shfl(w0v, k + 2), wd0 = __shfl(w0v, k + 3);
      float wa1 = __shfl(w1v, k),     wb1 = __shfl(w1v, k + 1);
      float wc1 = __shfl(w1v, k + 2), wd1 = __shfl(w1v, k + 3);
      const float* pa = xw + (size_t)sa * 128 + lane;
      const float* pb = xw + (size_t)sb * 128 + lane;
      const float* pc = xw + (size_t)sc * 128 + lane;
      const float* pd = xw + (size_t)sd * 128 + lane;
      float xa0 = pa[0], xa1 = pa[64];
      float xb0 = pb[0], xb1 = pb[64];
      float xc0 = pc[0], xc1 = pc[64];
      float xd0 = pd[0], xd1 = pd[64];
      acc0 = fmaf(wa0, xa0, acc0); acc1 = fmaf(wa1, xa1, acc1);
      acc0 = fmaf(wb0, xb0, acc0); acc1 = fmaf(wb1, xb1, acc1);
      acc0 = fmaf(wc0, xc0, acc0); acc1 = fmaf(wc1, xc1, acc1);
      acc0 = fmaf(wd0, xd0, acc0); acc1 = fmaf(wd1, xd1, acc1);
    }
    for (; k < cnt; ++k) {
      int s = __shfl(srcv, k);
      float w0 = __shfl(w0v, k);
      float w1 = __shfl(w1v, k);
      const float* p = xw + (size_t)s * 128 + lane;
      acc0 = fmaf(w0, p[0], acc0);
      acc1 = fmaf(w1, p[64], acc1);
    }
  }
  unsigned short* ap = agg + (size_t)node * 128;
  ap[lane] = f2bf(acc0);
  ap[64 + lane] = f2bf(acc1);
}

// ---------------- final_mlp: tiled GEMM, swizzled LDS, bf16 A-input ---------
__global__ __launch_bounds__(256) void final_mlp(
    const unsigned short* __restrict__ agg0, const unsigned short* __restrict__ agg1,
    const unsigned short* __restrict__ agg2, const float* __restrict__ bias0,
    const float* __restrict__ bias1, const float* __restrict__ bias2,
    const float* __restrict__ Wc1, const float* __restrict__ bc1,
    const float* __restrict__ Wc2, const float* __restrict__ bc2,
    float* __restrict__ out, int Nn) {
  __shared__ __align__(16) float xs[TKK][TM];
  __shared__ __align__(16) float4 wsB[TKK][TN/4];
  __shared__ float red[TM][17];
  const int tid = threadIdx.x;
  const int tx = tid & 15;
  const int ty = tid >> 4;
  const int row0 = blockIdx.x * TM;
  float acc[4][8];
#pragma unroll
  for (int r = 0; r < 4; ++r)
#pragma unroll
    for (int c = 0; c < 8; ++c) acc[r][c] = 0.f;

  const int lr = tid >> 2;
  const int lk = (tid & 3) * 8;
  const int wr = tid >> 3;
  const int bb = (tid & 7) * 4;
  const int xcol = lr ^ (((lk >> 3) & 1) * 16);
  const int p0 = (tx * 2) ^ (2 * ((tx * 2) >> 3));
  const int p1 = (tx * 2 + 1) ^ (2 * ((tx * 2 + 1) >> 3));

  for (int k0 = 0; k0 < 384; k0 += TKK) {
    int row = row0 + lr; if (row >= Nn) row = Nn - 1;
    const int kg = k0 + lk;
    const int sel = kg >> 7, q = kg & 127;
    const unsigned short* aggp = (sel == 0) ? agg0 : (sel == 1) ? agg1 : agg2;
    const float* bp   = (sel == 0) ? bias0 : (sel == 1) ? bias1 : bias2;
    uint4 raw = *(const uint4*)(aggp + (size_t)row * 128 + q);   // 8 bf16
    float4 ba  = *(const float4*)(bp + q);
    float4 bbv = *(const float4*)(bp + q + 4);
    float4 xa, xb;
    xa.x = elu1(bf2f(raw.x & 0xFFFF) + ba.x);
    xa.y = elu1(bf2f(raw.x >> 16)    + ba.y);
    xa.z = elu1(bf2f(raw.y & 0xFFFF) + ba.z);
    xa.w = elu1(bf2f(raw.y >> 16)    + ba.w);
    xb.x = elu1(bf2f(raw.z & 0xFFFF) + bbv.x);
    xb.y = elu1(bf2f(raw.z >> 16)    + bbv.y);
    xb.z = elu1(bf2f(raw.w & 0xFFFF) + bbv.z);
    xb.w = elu1(bf2f(raw.w >> 16)    + bbv.w);
    const float4* wp = (const float4*)(Wc1 + (size_t)(k0 + wr) * TN + bb * 4);
    float4 w0 = wp[0], w1 = wp[1], w2 = wp[2], w3 = wp[3];
    __syncthreads();
    xs[lk + 0][xcol] = xa.x; xs[lk + 1][xcol] = xa.y;
    xs[lk + 2][xcol] = xa.z; xs[lk + 3][xcol] = xa.w;
    xs[lk + 4][xcol] = xb.x; xs[lk + 5][xcol] = xb.y;
    xs[lk + 6][xcol] = xb.z; xs[lk + 7][xcol] = xb.w;
    {
      int b0i = bb + 0; wsB[wr][b0i ^ (2 * (b0i >> 3))] = w0;
      int b1i = bb + 1; wsB[wr][b1i ^ (2 * (b1i >> 3))] = w1;
      int b2i = bb + 2; wsB[wr][b2i ^ (2 * (b2i >> 3))] = w2;
      int b3i = bb + 3; wsB[wr][b3i ^ (2 * (b3i >> 3))] = w3;
    }
    __syncthreads();
#pragma unroll
    for (int k = 0; k < TKK; ++k) {
      const int acol = (ty * 4) ^ (((k >> 3) & 1) * 16);
      float4 a = *(const float4*)&xs[k][acol];
      float4 b0 = wsB[k][p0];
      float4 b1 = wsB[k][p1];
      float av[4] = {a.x, a.y, a.z, a.w};
      float bv[8] = {b0.x, b0.y, b0.z, b0.w, b1.x, b1.y, b1.z, b1.w};
#pragma unroll
      for (int r = 0; r < 4; ++r)
#pragma unroll
        for (int c = 0; c < 8; ++c)
          acc[r][c] = fmaf(av[r], bv[c], acc[r][c]);
    }
  }

  float bcv[8], w2v[8];
#pragma unroll
  for (int c = 0; c < 8; ++c) {
    bcv[c] = bc1[tx * 8 + c];
    w2v[c] = Wc2[tx * 8 + c];
  }
#pragma unroll
  for (int r = 0; r < 4; ++r) {
    float p = 0.f;
#pragma unroll
    for (int c = 0; c < 8; ++c)
      p = fmaf(fmaxf(acc[r][c] + bcv[c], 0.f), w2v[c], p);
    red[ty * 4 + r][tx] = p;
  }
  __syncthreads();
  if (tid < TM) {
    float s = 0.f;
#pragma unroll
    for (int i = 0; i < 16; ++i) s += red[tid][i];
    int n = row0 + tid;
    if (n < Nn) out[n] = s + bc2[0];
  }
}

// ---------------------------------------------------------------------------
extern "C" void kernel_launch(void* const* d_in, const int* in_sizes, int n_in,
                              void* d_out, int out_size, void* d_ws, size_t ws_size,
                              hipStream_t stream) {
  const int Nn = out_size;            // 40000
  const int E0 = in_sizes[1] / 2;
  const int E1 = in_sizes[7] / 2;
  const int E2 = in_sizes[13] / 2;
  const int totE = E0 + E1 + E2;
  const int Nt = 3 * Nn;
  const int nbpc = (Nn + 127) / 128;  // 313 buckets per category
  const int NB = 3 * nbpc;            // 939
  const int totAdj = totE + Nt;       // 1.92M

  // ws budget (~104 MB total; R9's 134.8 MB overflowed the workspace):
  char* base = (char*)d_ws;
  size_t off = 0;
  auto carve = [&](size_t bytes) -> void* {
    off = (off + 255) & ~(size_t)255;
    void* p = base + off;
    off += bytes;
    return p;
  };
  float* xw      = (float*)carve((size_t)Nn * 128 * 4);          // 20.5 MB
  unsigned short* agg3 = (unsigned short*)carve((size_t)Nt * 128 * 2); // 30.7 MB
  float* a_src3  = (float*)carve((size_t)Nt * 2 * 4);
  float* a_dst3  = (float*)carve((size_t)Nt * 2 * 4);
  int*   bktCnt  = (int*)carve((size_t)NB * SLICES * 16 * 4);    // 3.85 MB
  int2*  offcnt3 = (int2*)carve((size_t)Nt * 8);
  int*   bkt     = (int*)carve((size_t)NB * BSTG * 4);           // 23.1 MB
  int*   adjS    = (int*)carve((size_t)totAdj * 4);              // 7.7 MB
  float2* wEdge  = (float2*)carve((size_t)totAdj * 8);           // 15.4 MB
  int*   totB    = (int*)carve((size_t)NB * 4);
  int*   baseB   = (int*)carve((size_t)NB * 4);
  (void)ws_size; (void)n_in;

  const int* ei0 = (const int*)d_in[1];
  const int* ei1 = (const int*)d_in[7];
  const int* ei2 = (const int*)d_in[13];

  // adjacency build + compaction bases
  const int ncnt = NB * SLICES * 16;
  zeroB<<<(ncnt + 255) / 256, 256, 0, stream>>>(bktCnt, ncnt);
  scatter_b<<<(totAdj + 255) / 256, 256, 0, stream>>>(
      ei0, ei1, ei2, E0, E1, E2, Nn, nbpc, bktCnt, bkt);
  redbkt<<<NB, 64, 0, stream>>>(bktCnt, totB);
  scanbkt<<<1, 1024, 0, stream>>>(totB, baseB, NB);

  for (int cat = 0; cat < 3; ++cat) {
    const float* x   = (const float*)d_in[6 * cat + 0];
    const float* W   = (const float*)d_in[6 * cat + 2];
    const float* ats = (const float*)d_in[6 * cat + 3];
    const float* atd = (const float*)d_in[6 * cat + 4];
    const int K = in_sizes[6 * cat] / Nn;
    float* a_src_c = a_src3 + (size_t)cat * Nn * 2;
    float* a_dst_c = a_dst3 + (size_t)cat * Nn * 2;

    gemm_att<<<(Nn + TM - 1) / TM, 256, 0, stream>>>(
        x, W, ats, atd, xw, a_src_c, a_dst_c, Nn, K);
    build_w<<<nbpc, 256, 0, stream>>>(
        bkt, bktCnt, baseB, (const float2*)a_src_c, (const float2*)a_dst_c,
        adjS, wEdge, offcnt3, Nn, nbpc, cat);
    aggregate<<<((size_t)Nn * 64 + 255) / 256, 256, 0, stream>>>(
        xw, offcnt3 + (size_t)cat * Nn, adjS, wEdge,
        agg3 + (size_t)cat * Nn * 128, Nn);
  }

  final_mlp<<<(Nn + TM - 1) / TM, 256, 0, stream>>>(
      agg3, agg3 + (size_t)Nn * 128, agg3 + (size_t)2 * Nn * 128,
      (const float*)d_in[5], (const float*)d_in[11], (const float*)d_in[17],
      (const float*)d_in[18], (const float*)d_in[19],
      (const float*)d_in[20], (const float*)d_in[21],
      (float*)d_out, Nn);
}